// Round 2
// baseline (274.142 us; speedup 1.0000x reference)
//
#include <hip/hip_runtime.h>
#include <hip/hip_bf16.h>

// SelectiveDense: out[b,g,u] = relu(sum_k x[b, idx[g,k]] * kern[g,k,u] + bias[u])
// B=8192 D=4096 G=256 K=32 U=64. f32 in/out, bf16 MFMA compute.
// R1: 1024-thr blocks (4 waves/SIMD), operand-swapped MFMA (D[u][b]) -> dwordx4 stores.

#define B_ 8192
#define D_ 4096
#define G_ 256
#define K_ 32
#define U_ 64

typedef short v8s __attribute__((ext_vector_type(8)));     // 8 bf16 (4 VGPRs) MFMA A/B frag
typedef float f32x4 __attribute__((ext_vector_type(4)));   // MFMA C/D frag

__device__ __forceinline__ unsigned short f2bf(float f) {
    unsigned int u = __float_as_uint(f);
    u = (u + 0x7FFFu + ((u >> 16) & 1u)) >> 16;   // round-to-nearest-even
    return (unsigned short)u;
}

// Pre-pass: kernels f32 [G][K][U] -> bf16 frag layout [G][4 utiles][64 lanes][8]
// Used as MFMA *A* operand: lane l holds A[m=u_local=l&15][k=(l>>4)*8+j]
__global__ void prep_kb(const float* __restrict__ kern, unsigned short* __restrict__ kb) {
    int tid = blockIdx.x * blockDim.x + threadIdx.x;   // over G*K*U
    if (tid >= G_ * K_ * U_) return;
    int u = tid & (U_ - 1);
    int k = (tid >> 6) & (K_ - 1);
    int g = tid >> 11;
    int t = u >> 4;                       // u-tile 0..3
    int lane = ((k >> 3) << 4) | (u & 15);
    int j = k & 7;
    kb[((((g << 2) + t) << 6 | lane) << 3) | j] = f2bf(kern[tid]);
}

#define XS 4104   // LDS row stride in ushorts: 8208B -> bank shift 4/row, rows 16B-aligned

__global__ void __launch_bounds__(1024) sdense(
        const float* __restrict__ x, const unsigned short* __restrict__ kb,
        const float* __restrict__ bias, const int* __restrict__ idx,
        float* __restrict__ out) {
    extern __shared__ unsigned short lx[];   // [16][XS] bf16 x rows
    const int tid = threadIdx.x;
    const int b0 = blockIdx.x << 4;
    const int lane = tid & 63;
    const int w = tid >> 6;               // wave 0..15

    // ---- stage 16 rows of x (f32 -> bf16): one wave per row, coalesced ----
    {
        const float* xr = x + (size_t)(b0 + w) * D_;
        unsigned short* lr = lx + w * XS;
        #pragma unroll
        for (int i = 0; i < 8; ++i) {
            int col = (i << 9) + (lane << 3);      // 8 floats / lane / iter
            float4 v0 = *(const float4*)(xr + col);
            float4 v1 = *(const float4*)(xr + col + 4);
            union { unsigned short u[8]; v8s v; } st;
            st.u[0] = f2bf(v0.x); st.u[1] = f2bf(v0.y);
            st.u[2] = f2bf(v0.z); st.u[3] = f2bf(v0.w);
            st.u[4] = f2bf(v1.x); st.u[5] = f2bf(v1.y);
            st.u[6] = f2bf(v1.z); st.u[7] = f2bf(v1.w);
            *(v8s*)(lr + col) = st.v;              // 16B ds_write, conflict-free
        }
    }
    __syncthreads();

    // ---- per-wave: 16 g's; per g: gather B-frag from LDS, 4 MFMAs, 4 dwordx4 stores ----
    const int grp = lane >> 4;            // 0..3
    const int l15 = lane & 15;
    const int rowb = l15 * XS;            // B-operand: lane gathers x row b=l15, k=grp*8+j
    const int kk0 = grp << 3;

    float4 bias_v[4];
    #pragma unroll
    for (int t = 0; t < 4; ++t) bias_v[t] = *(const float4*)(bias + (t << 4) + (grp << 2));

    const v8s* kbv = (const v8s*)kb;

    for (int gi = 0; gi < 16; ++gi) {
        const int g = (w << 4) + gi;
        const int4* ip = (const int4*)(idx + (g << 5) + kk0);
        int4 ia = ip[0], ib = ip[1];

        union { unsigned short u[8]; v8s v; } Bf;  // B[k=grp*8+j][n=b=l15]
        Bf.u[0] = lx[rowb + ia.x]; Bf.u[1] = lx[rowb + ia.y];
        Bf.u[2] = lx[rowb + ia.z]; Bf.u[3] = lx[rowb + ia.w];
        Bf.u[4] = lx[rowb + ib.x]; Bf.u[5] = lx[rowb + ib.y];
        Bf.u[6] = lx[rowb + ib.z]; Bf.u[7] = lx[rowb + ib.w];

        const v8s* kg = kbv + ((g << 2) << 6) + lane;
        f32x4 acc[4];
        #pragma unroll
        for (int t = 0; t < 4; ++t) {
            v8s Af = kg[t << 6];                   // A[m=u_local][k]
            f32x4 z = {0.f, 0.f, 0.f, 0.f};
            acc[t] = __builtin_amdgcn_mfma_f32_16x16x32_bf16(Af, Bf.v, z, 0, 0, 0);
        }

        // D: col=l15 -> b, row=grp*4+r -> u_local. 4 consecutive u per lane -> float4 store.
        float* ob = out + (size_t)(b0 + l15) * (G_ * U_) + (g << 6) + (grp << 2);
        #pragma unroll
        for (int t = 0; t < 4; ++t) {
            f32x4 a = acc[t];
            float4 v;
            v.x = a[0] + bias_v[t].x; v.y = a[1] + bias_v[t].y;
            v.z = a[2] + bias_v[t].z; v.w = a[3] + bias_v[t].w;
            v.x = v.x > 0.f ? v.x : 0.f;
            v.y = v.y > 0.f ? v.y : 0.f;
            v.z = v.z > 0.f ? v.z : 0.f;
            v.w = v.w > 0.f ? v.w : 0.f;
            *(float4*)(ob + (t << 4)) = v;
        }
    }
}

extern "C" void kernel_launch(void* const* d_in, const int* in_sizes, int n_in,
                              void* d_out, int out_size, void* d_ws, size_t ws_size,
                              hipStream_t stream) {
    const float* x    = (const float*)d_in[0];
    const float* kern = (const float*)d_in[1];
    const float* bias = (const float*)d_in[2];
    const int*   idx  = (const int*)d_in[3];
    float* out = (float*)d_out;
    unsigned short* kb = (unsigned short*)d_ws;   // 1 MiB bf16 kernel frags

    prep_kb<<<(G_ * K_ * U_ + 255) / 256, 256, 0, stream>>>(kern, kb);
    sdense<<<B_ / 16, 1024, 16 * XS * sizeof(unsigned short), stream>>>(x, kb, bias, idx, out);
}

// Round 3
// 204.984 us; speedup vs baseline: 1.3374x; 1.3374x over previous
//
#include <hip/hip_runtime.h>
#include <hip/hip_bf16.h>

// SelectiveDense: out[b,g,u] = relu(sum_k x[b, idx[g,k]] * kern[g,k,u] + bias[u])
// B=8192 D=4096 G=256 K=32 U=64. f32 in/out, bf16 MFMA compute.
// R2: write-locality design — 8 waves interleave g (mod 8) in lockstep (raw s_barrier)
//     so each b-row gets ONE sweeping ~2KB write window (HBM page-hit friendly).

#define B_ 8192
#define D_ 4096
#define G_ 256
#define K_ 32
#define U_ 64

typedef short v8s __attribute__((ext_vector_type(8)));     // 8 bf16 (4 VGPRs) MFMA A/B frag
typedef float f32x4 __attribute__((ext_vector_type(4)));   // MFMA C/D frag

__device__ __forceinline__ unsigned short f2bf(float f) {
    unsigned int u = __float_as_uint(f);
    u = (u + 0x7FFFu + ((u >> 16) & 1u)) >> 16;   // round-to-nearest-even
    return (unsigned short)u;
}

// Pre-pass: kernels f32 [G][K][U] -> bf16 frag layout [G][4 utiles][64 lanes][8]
// MFMA B operand: lane l holds B[k=(l>>4)*8+j][col=u_local=l&15]
__global__ void prep_kb(const float* __restrict__ kern, unsigned short* __restrict__ kb) {
    int tid = blockIdx.x * blockDim.x + threadIdx.x;   // over G*K*U
    if (tid >= G_ * K_ * U_) return;
    int u = tid & (U_ - 1);
    int k = (tid >> 6) & (K_ - 1);
    int g = tid >> 11;
    int t = u >> 4;                       // u-tile 0..3
    int lane = ((k >> 3) << 4) | (u & 15);
    int j = k & 7;
    kb[((((g << 2) + t) << 6 | lane) << 3) | j] = f2bf(kern[tid]);
}

#define XS 4100   // LDS row stride (ushorts): bank shift 2/row -> gather ~conflict-free

__global__ void __launch_bounds__(512) sdense(
        const float* __restrict__ x, const unsigned short* __restrict__ kb,
        const float* __restrict__ bias, const int* __restrict__ idx,
        float* __restrict__ out) {
    extern __shared__ unsigned short lx[];   // [16][XS] bf16 x rows
    const int tid = threadIdx.x;
    const int b0 = blockIdx.x << 4;
    const int lane = tid & 63;
    const int w = tid >> 6;               // wave 0..7

    // ---- stage 16 rows of x (f32 -> bf16): wave w -> rows 2w, 2w+1 ----
    {
        const int row = (w << 1) + (lane >> 5);
        const int l32 = lane & 31;
        const float* xr = x + (size_t)(b0 + row) * D_;
        unsigned short* lr = lx + row * XS;
        #pragma unroll
        for (int i = 0; i < 16; ++i) {
            int col = (i << 8) + (l32 << 3);       // 8 floats / lane / iter
            float4 v0 = *(const float4*)(xr + col);
            float4 v1 = *(const float4*)(xr + col + 4);
            union { unsigned short u[8]; v8s v; } st;
            st.u[0] = f2bf(v0.x); st.u[1] = f2bf(v0.y);
            st.u[2] = f2bf(v0.z); st.u[3] = f2bf(v0.w);
            st.u[4] = f2bf(v1.x); st.u[5] = f2bf(v1.y);
            st.u[6] = f2bf(v1.z); st.u[7] = f2bf(v1.w);
            *(v8s*)(lr + col) = st.v;              // 16B ds_write
        }
    }
    __syncthreads();

    // ---- g-loop: wave w handles g = 8q + w, lockstep across waves ----
    const int grp = lane >> 4;            // 0..3
    const int l15 = lane & 15;
    const int rowb = l15 * XS;            // A-operand: lane gathers x row b=l15
    const int kk0 = grp << 3;

    float bias_v[4];
    #pragma unroll
    for (int t = 0; t < 4; ++t) bias_v[t] = bias[(t << 4) + l15];

    const v8s* kbv = (const v8s*)kb;

    // software pipeline: prefetch idx + kb one iteration ahead
    int4 ia, ib;
    v8s k0, k1, k2, k3;
    {
        const int g = w;
        const int4* ip = (const int4*)(idx + (g << 5) + kk0);
        ia = ip[0]; ib = ip[1];
        const v8s* kg = kbv + (g << 8) + lane;
        k0 = kg[0]; k1 = kg[64]; k2 = kg[128]; k3 = kg[192];
    }

    for (int q = 0; q < 32; ++q) {
        const int g = (q << 3) + w;

        // prefetch next (wraps harmlessly to first on last iter)
        const int gn = (q < 31) ? (g + 8) : w;
        const int4* ipn = (const int4*)(idx + (gn << 5) + kk0);
        int4 na = ipn[0], nb = ipn[1];
        const v8s* kgn = kbv + (gn << 8) + lane;
        v8s n0 = kgn[0], n1 = kgn[64], n2 = kgn[128], n3 = kgn[192];

        // gather A frag: A[m=b=l15][k=grp*8+j]
        union { unsigned short u[8]; v8s v; } A;
        A.u[0] = lx[rowb + ia.x]; A.u[1] = lx[rowb + ia.y];
        A.u[2] = lx[rowb + ia.z]; A.u[3] = lx[rowb + ia.w];
        A.u[4] = lx[rowb + ib.x]; A.u[5] = lx[rowb + ib.y];
        A.u[6] = lx[rowb + ib.z]; A.u[7] = lx[rowb + ib.w];

        f32x4 acc[4];
        {
            f32x4 z = {0.f, 0.f, 0.f, 0.f};
            acc[0] = __builtin_amdgcn_mfma_f32_16x16x32_bf16(A.v, k0, z, 0, 0, 0);
            acc[1] = __builtin_amdgcn_mfma_f32_16x16x32_bf16(A.v, k1, z, 0, 0, 0);
            acc[2] = __builtin_amdgcn_mfma_f32_16x16x32_bf16(A.v, k2, z, 0, 0, 0);
            acc[3] = __builtin_amdgcn_mfma_f32_16x16x32_bf16(A.v, k3, z, 0, 0, 0);
        }

        // D: row=b=grp*4+r, col=u=t*16+l15. Store r-outer, t-inner:
        // per b-row, 4 back-to-back 64B stores sweep 256B sequentially.
        float* ob = out + (size_t)(b0 + (grp << 2)) * (G_ * U_) + (g << 6) + l15;
        #pragma unroll
        for (int r = 0; r < 4; ++r) {
            float* obr = ob + (size_t)r * (G_ * U_);
            #pragma unroll
            for (int t = 0; t < 4; ++t) {
                float v = acc[t][r] + bias_v[t];
                obr[t << 4] = v > 0.f ? v : 0.f;
            }
        }

        ia = na; ib = nb; k0 = n0; k1 = n1; k2 = n2; k3 = n3;

        // raw barrier: keep waves' g-windows aligned WITHOUT draining stores
        // (__syncthreads would emit s_waitcnt vmcnt(0) and serialize retirement)
        __builtin_amdgcn_s_barrier();
    }
}

extern "C" void kernel_launch(void* const* d_in, const int* in_sizes, int n_in,
                              void* d_out, int out_size, void* d_ws, size_t ws_size,
                              hipStream_t stream) {
    const float* x    = (const float*)d_in[0];
    const float* kern = (const float*)d_in[1];
    const float* bias = (const float*)d_in[2];
    const int*   idx  = (const int*)d_in[3];
    float* out = (float*)d_out;
    unsigned short* kb = (unsigned short*)d_ws;   // 1 MiB bf16 kernel frags

    prep_kb<<<(G_ * K_ * U_ + 255) / 256, 256, 0, stream>>>(kern, kb);
    sdense<<<B_ / 16, 512, 16 * XS * sizeof(unsigned short), stream>>>(x, kb, bias, idx, out);
}

// Round 4
// 176.671 us; speedup vs baseline: 1.5517x; 1.1603x over previous
//
#include <hip/hip_runtime.h>
#include <hip/hip_bf16.h>

// SelectiveDense: out[b,g,u] = relu(sum_k x[b, idx[g,k]] * kern[g,k,u] + bias[u])
// B=8192 D=4096 G=256 K=32 U=64. f32 in/out, bf16 MFMA compute.
// R3: accumulate QG=4 g's in VGPRs before storing -> per output row, each wave
//     writes 1KB contiguous (16x64B sequential) per super-iter; block window 8KB/row.
//     DRAM page-locality fix on top of R2's lockstep g-window design.

#define B_ 8192
#define D_ 4096
#define G_ 256
#define K_ 32
#define U_ 64

typedef short v8s __attribute__((ext_vector_type(8)));     // 8 bf16 (4 VGPRs) MFMA A/B frag
typedef float f32x4 __attribute__((ext_vector_type(4)));   // MFMA C/D frag

__device__ __forceinline__ unsigned short f2bf(float f) {
    unsigned int u = __float_as_uint(f);
    u = (u + 0x7FFFu + ((u >> 16) & 1u)) >> 16;   // round-to-nearest-even
    return (unsigned short)u;
}

// Pre-pass: kernels f32 [G][K][U] -> bf16 frag layout [G][4 utiles][64 lanes][8]
// MFMA B operand: lane l holds B[k=(l>>4)*8+j][col=u_local=l&15]
__global__ void prep_kb(const float* __restrict__ kern, unsigned short* __restrict__ kb) {
    int tid = blockIdx.x * blockDim.x + threadIdx.x;   // over G*K*U
    if (tid >= G_ * K_ * U_) return;
    int u = tid & (U_ - 1);
    int k = (tid >> 6) & (K_ - 1);
    int g = tid >> 11;
    int t = u >> 4;                       // u-tile 0..3
    int lane = ((k >> 3) << 4) | (u & 15);
    int j = k & 7;
    kb[((((g << 2) + t) << 6 | lane) << 3) | j] = f2bf(kern[tid]);
}

#define XS 4100   // LDS row stride (ushorts): bank shift 2/row -> gather ~conflict-free

__global__ void __launch_bounds__(512) sdense(
        const float* __restrict__ x, const unsigned short* __restrict__ kb,
        const float* __restrict__ bias, const int* __restrict__ idx,
        float* __restrict__ out) {
    extern __shared__ unsigned short lx[];   // [16][XS] bf16 x rows
    const int tid = threadIdx.x;
    const int b0 = blockIdx.x << 4;
    const int lane = tid & 63;
    const int w = tid >> 6;               // wave 0..7

    // ---- stage 16 rows of x (f32 -> bf16): wave w -> rows 2w, 2w+1 ----
    {
        const int row = (w << 1) + (lane >> 5);
        const int l32 = lane & 31;
        const float* xr = x + (size_t)(b0 + row) * D_;
        unsigned short* lr = lx + row * XS;
        #pragma unroll
        for (int i = 0; i < 16; ++i) {
            int col = (i << 8) + (l32 << 3);       // 8 floats / lane / iter
            float4 v0 = *(const float4*)(xr + col);
            float4 v1 = *(const float4*)(xr + col + 4);
            union { unsigned short u[8]; v8s v; } st;
            st.u[0] = f2bf(v0.x); st.u[1] = f2bf(v0.y);
            st.u[2] = f2bf(v0.z); st.u[3] = f2bf(v0.w);
            st.u[4] = f2bf(v1.x); st.u[5] = f2bf(v1.y);
            st.u[6] = f2bf(v1.z); st.u[7] = f2bf(v1.w);
            *(v8s*)(lr + col) = st.v;              // 16B ds_write
        }
    }
    __syncthreads();

    // ---- super-iter: wave w covers g in [32q+4w, 32q+4w+4); block window 32 g's ----
    const int grp = lane >> 4;            // 0..3
    const int l15 = lane & 15;
    const int rowb = l15 * XS;            // A-operand: lane gathers x row b=l15
    const int kk0 = grp << 3;

    float bias_v[4];
    #pragma unroll
    for (int t = 0; t < 4; ++t) bias_v[t] = bias[(t << 4) + l15];

    const v8s* kbv = (const v8s*)kb;

    for (int q = 0; q < 8; ++q) {
        const int g0 = (q << 5) + (w << 2);   // 32q + 4w

        // idx for 4 g's (L2-hot)
        int4 ia[4], ibb[4];
        #pragma unroll
        for (int j = 0; j < 4; ++j) {
            const int4* ip = (const int4*)(idx + ((g0 + j) << 5) + kk0);
            ia[j] = ip[0]; ibb[j] = ip[1];
        }
        // kb frags for 4 g's (L2-hot)
        v8s kf[4][4];
        #pragma unroll
        for (int j = 0; j < 4; ++j) {
            const v8s* kg = kbv + ((g0 + j) << 8) + lane;
            kf[j][0] = kg[0]; kf[j][1] = kg[64]; kf[j][2] = kg[128]; kf[j][3] = kg[192];
        }

        // gather + MFMA, accumulate 4 g's of output in VGPRs
        f32x4 acc[4][4];
        #pragma unroll
        for (int j = 0; j < 4; ++j) {
            union { unsigned short u[8]; v8s v; } A;  // A[m=b=l15][k=grp*8+jj]
            A.u[0] = lx[rowb + ia[j].x];  A.u[1] = lx[rowb + ia[j].y];
            A.u[2] = lx[rowb + ia[j].z];  A.u[3] = lx[rowb + ia[j].w];
            A.u[4] = lx[rowb + ibb[j].x]; A.u[5] = lx[rowb + ibb[j].y];
            A.u[6] = lx[rowb + ibb[j].z]; A.u[7] = lx[rowb + ibb[j].w];
            f32x4 z = {0.f, 0.f, 0.f, 0.f};
            #pragma unroll
            for (int t = 0; t < 4; ++t)
                acc[j][t] = __builtin_amdgcn_mfma_f32_16x16x32_bf16(A.v, kf[j][t], z, 0, 0, 0);
        }

        // store phase: r-outer; per row, 16 sequential 64B segments = 1KB contiguous
        #pragma unroll
        for (int r = 0; r < 4; ++r) {
            float* obr = out + (size_t)(b0 + (grp << 2) + r) * (G_ * U_) + (g0 << 6) + l15;
            #pragma unroll
            for (int j = 0; j < 4; ++j) {
                #pragma unroll
                for (int t = 0; t < 4; ++t) {
                    float v = acc[j][t][r] + bias_v[t];
                    obr[(j << 6) + (t << 4)] = v > 0.f ? v : 0.f;
                }
            }
        }

        // raw barrier keeps the 8 waves' g-windows aligned (no vmcnt drain)
        __builtin_amdgcn_s_barrier();
    }
}

extern "C" void kernel_launch(void* const* d_in, const int* in_sizes, int n_in,
                              void* d_out, int out_size, void* d_ws, size_t ws_size,
                              hipStream_t stream) {
    const float* x    = (const float*)d_in[0];
    const float* kern = (const float*)d_in[1];
    const float* bias = (const float*)d_in[2];
    const int*   idx  = (const int*)d_in[3];
    float* out = (float*)d_out;
    unsigned short* kb = (unsigned short*)d_ws;   // 1 MiB bf16 kernel frags

    prep_kb<<<(G_ * K_ * U_ + 255) / 256, 256, 0, stream>>>(kern, kb);
    sdense<<<B_ / 16, 512, 16 * XS * sizeof(unsigned short), stream>>>(x, kb, bias, idx, out);
}